// Round 9
// baseline (277.785 us; speedup 1.0000x reference)
//
#include <hip/hip_runtime.h>
#include <hip/hip_bf16.h>
#include <stdint.h>

#define T_SEQ 2048
#define EMB   512
#define NH    8
#define HEAD_ALL 4096   // NH*EMB

typedef __attribute__((ext_vector_type(8))) short short8;
typedef __attribute__((ext_vector_type(4))) float f32x4;

__device__ __forceinline__ unsigned short f2b(float f) {
    __hip_bfloat16 h = __float2bfloat16(f);
    return *reinterpret_cast<unsigned short*>(&h);
}
__device__ __forceinline__ float b2f(unsigned short u) {
    return __uint_as_float(((unsigned)u) << 16);
}
__device__ __forceinline__ void gload_lds16(const void* g, void* l) {
    __builtin_amdgcn_global_load_lds((__attribute__((address_space(1))) void*)(void*)(g),
                                     (__attribute__((address_space(3))) void*)(l), 16, 0, 0);
}
__device__ __forceinline__ void wg_barrier() {
    asm volatile("" ::: "memory");
    __builtin_amdgcn_s_barrier();
    asm volatile("" ::: "memory");
}

// ---------------- f32 -> bf16 convert, two tensors in one launch ----------------
__global__ void cvt_bf16_2(const float* __restrict__ a, const float* __restrict__ b,
                           unsigned short* __restrict__ oa, unsigned short* __restrict__ ob, int n8) {
    const float* in = blockIdx.y ? b : a;
    unsigned short* out = blockIdx.y ? ob : oa;
    int i = blockIdx.x * 256 + threadIdx.x;
    if (i >= n8) return;
    const f32x4* p = (const f32x4*)in + 2 * (size_t)i;
    f32x4 va = p[0], vb = p[1];
    uint4 o;
    o.x = (unsigned)f2b(va[0]) | ((unsigned)f2b(va[1]) << 16);
    o.y = (unsigned)f2b(va[2]) | ((unsigned)f2b(va[3]) << 16);
    o.z = (unsigned)f2b(vb[0]) | ((unsigned)f2b(vb[1]) << 16);
    o.w = (unsigned)f2b(vb[2]) | ((unsigned)f2b(vb[3]) << 16);
    *((uint4*)out + i) = o;
}

// ------- f32 [R][C] -> bf16 [C][R] transpose-convert, z selects source -------
__global__ void transpose_cvt3_f32(const float* __restrict__ w0, const float* __restrict__ w1,
                                   const float* __restrict__ w2, unsigned short* __restrict__ out,
                                   int R, int C, long outS) {
    __shared__ unsigned short t[64][66];
    const int z = blockIdx.z;
    const float* in = (z == 0) ? w0 : ((z == 1) ? w1 : w2);
    unsigned short* ob = out + (long)z * outS;
    const int tid = threadIdx.x;
    const int r0 = blockIdx.y * 64, c0 = blockIdx.x * 64;
#pragma unroll
    for (int it = 0; it < 4; ++it) {
        int flat = it * 256 + tid;
        int r = flat >> 4, c4 = flat & 15;
        f32x4 v = *(const f32x4*)(in + (long)(r0 + r) * C + c0 + c4 * 4);
#pragma unroll
        for (int w = 0; w < 4; ++w) t[r][c4 * 4 + w] = f2b(v[w]);
    }
    __syncthreads();
#pragma unroll
    for (int it = 0; it < 2; ++it) {
        int flat = it * 256 + tid;
        int rr = flat >> 3, c8 = flat & 7;
        unsigned u[4];
#pragma unroll
        for (int w = 0; w < 4; ++w) {
            unsigned short a = t[c8 * 8 + 2 * w][rr];
            unsigned short b = t[c8 * 8 + 2 * w + 1][rr];
            u[w] = (unsigned)a | ((unsigned)b << 16);
        }
        *(uint4*)(ob + (long)(c0 + rr) * R + r0 + c8 * 8) = make_uint4(u[0], u[1], u[2], u[3]);
    }
}

// ---------------- bf16 [R][C] -> bf16 [C][R] transpose, batched ----------------
__global__ void transpose_bf16(const unsigned short* __restrict__ in, unsigned short* __restrict__ out,
                               int R, int C, long inS, long outS) {
    __shared__ unsigned short t[64][66];
    const unsigned short* ib = in + (long)blockIdx.z * inS;
    unsigned short* ob = out + (long)blockIdx.z * outS;
    const int tid = threadIdx.x;
    const int r0 = blockIdx.y * 64, c0 = blockIdx.x * 64;
#pragma unroll
    for (int it = 0; it < 2; ++it) {
        int flat = it * 256 + tid;
        int r = flat >> 3, c8 = flat & 7;
        uint4 v = *(const uint4*)(ib + (long)(r0 + r) * C + c0 + c8 * 8);
        unsigned u[4] = {v.x, v.y, v.z, v.w};
#pragma unroll
        for (int w = 0; w < 4; ++w) {
            t[r][c8 * 8 + 2 * w]     = (unsigned short)(u[w] & 0xffff);
            t[r][c8 * 8 + 2 * w + 1] = (unsigned short)(u[w] >> 16);
        }
    }
    __syncthreads();
#pragma unroll
    for (int it = 0; it < 2; ++it) {
        int flat = it * 256 + tid;
        int rr = flat >> 3, c8 = flat & 7;
        unsigned u[4];
#pragma unroll
        for (int w = 0; w < 4; ++w)
            u[w] = (unsigned)t[c8 * 8 + 2 * w][rr] | ((unsigned)t[c8 * 8 + 2 * w + 1][rr] << 16);
        *(uint4*)(ob + (long)(c0 + rr) * R + r0 + c8 * 8) = make_uint4(u[0], u[1], u[2], u[3]);
    }
}

// ============== 8-phase double-buffered GEMM (proven; used for proj + final) ==============
template<int R_>
__device__ __forceinline__ void stage2(const unsigned short* __restrict__ src, int kfull,
                                       short* ldsbase, int i, int tid, int wid) {
#pragma unroll
    for (int s = 0; s < 2; ++s) {
        const int ii = i + s;
        const int r = ii * 64 + (tid >> 3);
        const int d = (tid & 7) * 16;                  // dest byte within 128B row
        const int sc = (d ^ ((r & 7) << 4)) >> 1;      // inverse-swizzled src col (elems)
        gload_lds16(src + (long)r * kfull + sc, ldsbase + ii * 4096 + wid * 512);
    }
}

// MODE 1: projections -> head-split bf16 [h][t][e]: batch0=V(x), 1=K(x), 2=Q(y)
// MODE 3: f32 split-K partial over K-slice batch
template<int BM, int BN, int KTILES, int MODE>
__global__ __launch_bounds__(512, 2)
void gemm8p(const unsigned short* __restrict__ A, const unsigned short* __restrict__ A2,
            const unsigned short* __restrict__ B, void* __restrict__ Cout,
            int kfull, float alpha, long As, long Bs, long Cs, int ldc)
{
    static_assert(KTILES >= 3, "pipeline needs >=3 K-tiles");
    constexpr int ATILE = BM * 64;
    constexpr int BTILE = BN * 64;
    constexpr int LA = BM / 64;
    constexpr int LB = BN / 64;
    constexpr int MF = BM / 32;
    constexpr int NF = BN / 64;
    constexpr int MFP = MF / 4;

    __shared__ __align__(16) short lds[2 * (ATILE + BTILE)];

    const int tid = threadIdx.x;
    const int wid = tid >> 6, lane = tid & 63;
    const int wm = wid >> 2, wn = wid & 3;
    const int fr = lane & 15, fq = lane >> 4;

    // T1: XCD chunk swizzle
    const int nwg = gridDim.x * gridDim.y * gridDim.z;
    int flat = blockIdx.x + gridDim.x * (blockIdx.y + gridDim.y * blockIdx.z);
    flat = (flat & 7) * (nwg >> 3) + (flat >> 3);
    const int bx = flat % gridDim.x;
    const int rem = flat / gridDim.x;
    const int by = rem % gridDim.y;
    const long batch = rem / gridDim.y;

    const int bm = by * BM, bn = bx * BN;

    const unsigned short* Ab;
    const unsigned short* Bb;
    int koff = 0;
    if constexpr (MODE == 1) { Ab = (batch == 2) ? A2 : A; Bb = B + batch * Bs; }
    else { Ab = A; Bb = B; koff = (int)batch * (KTILES * 64); }

    const unsigned short* Ag = Ab + (long)bm * kfull + koff;
    const unsigned short* Bg = Bb + (long)bn * kfull + koff;

    f32x4 acc[MF][NF];
#pragma unroll
    for (int i = 0; i < MF; i++)
#pragma unroll
        for (int j = 0; j < NF; j++) acc[i][j] = 0.f;

#pragma unroll
    for (int i = 0; i < LA; i += 2) stage2<BM>(Ag, kfull, lds, i, tid, wid);
#pragma unroll
    for (int i = 0; i < LB; i += 2) stage2<BN>(Bg, kfull, lds + 2 * ATILE, i, tid, wid);
#pragma unroll
    for (int i = 0; i < LB; i += 2) stage2<BN>(Bg + 64, kfull, lds + 2 * ATILE + BTILE, i, tid, wid);
    if constexpr (LB == 4) asm volatile("s_waitcnt vmcnt(4)" ::: "memory");
    else                   asm volatile("s_waitcnt vmcnt(2)" ::: "memory");
    wg_barrier();

#pragma unroll 2
    for (int t = 0; t < KTILES; ++t) {
        short* la  = lds + (t & 1) * ATILE;
        short* laN = lds + ((t + 1) & 1) * ATILE;
        short* lb  = lds + 2 * ATILE + (t & 1) * BTILE;
        const int kA = (t + 1) * 64;
        const int kB = (t + 2) * 64;

        short8 bfrag[NF][2];
#pragma unroll
        for (int q = 0; q < 4; ++q) {
            if (q == 0) {
#pragma unroll
                for (int nf = 0; nf < NF; ++nf)
#pragma unroll
                    for (int kk = 0; kk < 2; ++kk) {
                        const int r = wn * (BN / 4) + nf * 16 + fr;
                        const int cb = kk * 64 + fq * 16;
                        bfrag[nf][kk] = *(const short8*)(lb + r * 64 + ((cb ^ ((r & 7) << 4)) >> 1));
                    }
            }
            short8 afrag[MFP][2];
#pragma unroll
            for (int mf = 0; mf < MFP; ++mf)
#pragma unroll
                for (int kk = 0; kk < 2; ++kk) {
                    const int r = wm * (BM / 2) + q * (BM / 8) + mf * 16 + fr;
                    const int cb = kk * 64 + fq * 16;
                    afrag[mf][kk] = *(const short8*)(la + r * 64 + ((cb ^ ((r & 7) << 4)) >> 1));
                }
            if (t + 1 < KTILES) {
                if (q == 0) stage2<BM>(Ag + kA, kfull, laN, 0, tid, wid);
                if (q == 1 && LA == 4) stage2<BM>(Ag + kA, kfull, laN, 2, tid, wid);
            }
            if (t + 2 < KTILES) {
                if (q == 2) stage2<BN>(Bg + kB, kfull, lb, 0, tid, wid);
                if (q == 3 && LB == 4) stage2<BN>(Bg + kB, kfull, lb, 2, tid, wid);
            }
            wg_barrier();
            __builtin_amdgcn_s_setprio(1);
#pragma unroll
            for (int mf = 0; mf < MFP; ++mf)
#pragma unroll
                for (int nf = 0; nf < NF; ++nf)
#pragma unroll
                    for (int kk = 0; kk < 2; ++kk)
                        acc[q * MFP + mf][nf] = __builtin_amdgcn_mfma_f32_16x16x32_bf16(
                            afrag[mf][kk], bfrag[nf][kk], acc[q * MFP + mf][nf], 0, 0, 0);
            __builtin_amdgcn_s_setprio(0);
            if (q == 3) {
                if (t + 2 < KTILES) {
                    if constexpr (LB == 4) asm volatile("s_waitcnt vmcnt(4)" ::: "memory");
                    else                   asm volatile("s_waitcnt vmcnt(2)" ::: "memory");
                } else {
                    asm volatile("s_waitcnt vmcnt(0)" ::: "memory");
                }
            }
            wg_barrier();
        }
    }

#pragma unroll
    for (int m = 0; m < MF; ++m)
#pragma unroll
        for (int j = 0; j < 4; ++j) {
            const int row = bm + wm * (BM / 2) + m * 16 + fq * 4 + j;
#pragma unroll
            for (int n = 0; n < NF; ++n) {
                const int col = bn + wn * (BN / 4) + n * 16 + fr;
                const float v = acc[m][n][j] * alpha;
                if constexpr (MODE == 1) {
                    unsigned short* C = (unsigned short*)Cout + batch * Cs;
                    C[(long)(col >> 9) * ((long)T_SEQ * EMB) + (long)row * EMB + (col & 511)] = f2b(v);
                } else {
                    float* C = (float*)Cout + batch * ((long)T_SEQ * EMB);
                    C[(long)row * ldc + col] = v;
                }
            }
        }
}

// ============== fused attention: O = (exp(s*QK^T) @ V) / rowsum ==============
// Block = 64 q-rows x 1 head; 8 waves; grid (32 qb, 8 h), head-per-XCD swizzle.
// LDS: K[64kv][512e] @0 (64KB, swz (kv&7)<<4 per 1024B row),
//      VT[512d][64kv] @65536 (64KB, swz (d&7)<<4 per 128B row),
//      St[64q][64kv] bf16 @131072 (8KB, swz2 = ((q&7)<<4)^((q&8)<<2) per 128B row),
//      rs[4][64] f32 @139264.
// QK waves (rg=wid&1, ch=wid>>1): rows rg*32..+32 (2 m-frags, Q in 32 regs/lane),
//     kv cols ch*16..+16: each K-frag read ONCE per ks (16 reads/wave vs 32 --
//     halves the dominant LDS-read term). 2 k-split accs per m-frag.
// PV: wave owns d-slice wid*64..+64: 4m x 4n frags x 2 ksteps from St + VT.
// Pipeline: vmcnt(8) @top (K_t ready, VT_t in flight); vmcnt(0) pre-PV;
// stage K_{t+1} after B2 (K_t reads retired); stage VT_{t+1} after B3.
__global__ __launch_bounds__(512, 2)
void attn_fused(const unsigned short* __restrict__ Qg, const unsigned short* __restrict__ Kg,
                const unsigned short* __restrict__ VTg, unsigned short* __restrict__ Og,
                float scale)
{
    __shared__ __align__(16) short lds[70144];   // 140288 B
    float* rs = (float*)(lds + 69632);           // [4][64] @byte 139264
    char* ldsb = (char*)lds;

    const int tid = threadIdx.x;
    const int wid = tid >> 6, lane = tid & 63;
    const int fr = lane & 15, fq = lane >> 4;
    const int rg = wid & 1, ch = wid >> 1;       // QK role: 32 q-rows, 16 kv-cols

    // head-per-XCD: orig%8 = XCD (round-robin dispatch) -> head = f>>5
    const int orig = blockIdx.x + 32 * blockIdx.y;
    const int f = (orig & 7) * 32 + (orig >> 3);
    const int qb = f & 31, h = f >> 5;
    const long TE = (long)T_SEQ * EMB;
    const unsigned short* Qh = Qg + (long)h * TE + (long)(qb * 64) * EMB;
    const unsigned short* Kh = Kg + (long)h * TE;
    const unsigned short* Vh = VTg + (long)h * TE;

    // Q fragments in registers: 2 m-frags, rows rg*32 + mm*16 + fr, k = ks*32 + fq*8
    short8 qreg[2][16];
#pragma unroll
    for (int mm = 0; mm < 2; ++mm)
#pragma unroll
        for (int ks = 0; ks < 16; ++ks)
            qreg[mm][ks] = *(const short8*)(Qh + (long)(rg * 32 + mm * 16 + fr) * EMB + ks * 32 + fq * 8);

    // ---- staging (dest = wave-uniform base; HW adds lane*16) ----
    auto stageK = [&](int kb) {
#pragma unroll
        for (int it = 0; it < 8; ++it) {
            const int c = it * 512 + tid;
            const int kv = c >> 6, s = c & 63;
            gload_lds16(Kh + (long)(kb * 64 + kv) * EMB + (((s * 16) ^ ((kv & 7) << 4)) >> 1),
                        lds + (it * 512 + wid * 64) * 8);
        }
    };
    auto stageV = [&](int kb) {
#pragma unroll
        for (int it = 0; it < 8; ++it) {
            const int c = it * 512 + tid;
            const int d = c >> 3, s = c & 7;
            gload_lds16(Vh + (long)d * T_SEQ + kb * 64 + (((s * 16) ^ ((d & 7) << 4)) >> 1),
                        lds + 32768 + (it * 512 + wid * 64) * 8);
        }
    };

    f32x4 oacc[4][4];
#pragma unroll
    for (int m = 0; m < 4; ++m)
#pragma unroll
        for (int n = 0; n < 4; ++n) oacc[m][n] = 0.f;
    float rsum[2][4];
#pragma unroll
    for (int mm = 0; mm < 2; ++mm)
#pragma unroll
        for (int j = 0; j < 4; ++j) rsum[mm][j] = 0.f;

    stageK(0);
    stageV(0);

#pragma unroll 1
    for (int t = 0; t < 32; ++t) {
        asm volatile("s_waitcnt vmcnt(8)" ::: "memory");   // K_t landed
        wg_barrier();                                       // B1: K_t visible

        // ---- QK^T: one B-frag per ks, used by both m-frags; 2 k-split accs ----
        f32x4 sacc[2][2];
#pragma unroll
        for (int mm = 0; mm < 2; ++mm) { sacc[mm][0] = 0.f; sacc[mm][1] = 0.f; }
        const int kv = ch * 16 + fr;
#pragma unroll
        for (int ks = 0; ks < 16; ++ks) {
            const short8 bfr = *(const short8*)(ldsb + kv * 1024 +
                                ((ks * 64 + fq * 16) ^ ((kv & 7) << 4)));
#pragma unroll
            for (int mm = 0; mm < 2; ++mm)
                sacc[mm][ks & 1] = __builtin_amdgcn_mfma_f32_16x16x32_bf16(
                    qreg[mm][ks], bfr, sacc[mm][ks & 1], 0, 0, 0);
        }
        // ---- exp + rowsum + S~ -> LDS (swz2: disjoint 32B regions per fq-group) ----
#pragma unroll
        for (int mm = 0; mm < 2; ++mm)
#pragma unroll
            for (int j = 0; j < 4; ++j) {
                const float v = __expf(scale * (sacc[mm][0][j] + sacc[mm][1][j]));
                rsum[mm][j] += v;
                const int row = rg * 32 + mm * 16 + fq * 4 + j;
                *(unsigned short*)(ldsb + 131072 + row * 128 +
                    ((kv * 2) ^ ((row & 7) << 4) ^ ((row & 8) << 2))) = f2b(v);
            }
        asm volatile("s_waitcnt lgkmcnt(0)" ::: "memory");
        asm volatile("s_waitcnt vmcnt(0)" ::: "memory");    // VT_t landed
        wg_barrier();                                        // B2: S~ + VT_t visible; K_t reads retired
        if (t + 1 < 32) stageK(t + 1);

        // ---- PV: O[64 x 64(d-slice)] += S~ @ V ----
#pragma unroll
        for (int kk = 0; kk < 2; ++kk) {
            short8 sa[4], vb[4];
#pragma unroll
            for (int m = 0; m < 4; ++m) {
                const int row = m * 16 + fr;
                sa[m] = *(const short8*)(ldsb + 131072 + row * 128 +
                          ((kk * 64 + fq * 16) ^ ((row & 7) << 4) ^ ((row & 8) << 2)));
            }
#pragma unroll
            for (int n = 0; n < 4; ++n) {
                const int d = wid * 64 + n * 16 + fr;
                vb[n] = *(const short8*)(ldsb + 65536 + d * 128 +
                          ((kk * 64 + fq * 16) ^ ((d & 7) << 4)));
            }
            __builtin_amdgcn_s_setprio(1);
#pragma unroll
            for (int m = 0; m < 4; ++m)
#pragma unroll
                for (int n = 0; n < 4; ++n)
                    oacc[m][n] = __builtin_amdgcn_mfma_f32_16x16x32_bf16(
                        sa[m], vb[n], oacc[m][n], 0, 0, 0);
            __builtin_amdgcn_s_setprio(0);
        }
        wg_barrier();                                        // B3: VT_t + S~ reads retired
        if (t + 1 < 32) stageV(t + 1);
    }

    // ---- rowsum reduce: per-wave kv-slice sums -> rs[ch][row]; combine 4 slices ----
#pragma unroll
    for (int mm = 0; mm < 2; ++mm)
#pragma unroll
        for (int j = 0; j < 4; ++j) {
            float v = rsum[mm][j];
            v += __shfl_xor(v, 1);
            v += __shfl_xor(v, 2);
            v += __shfl_xor(v, 4);
            v += __shfl_xor(v, 8);
            if (fr == 0) rs[ch * 64 + rg * 32 + mm * 16 + fq * 4 + j] = v;
        }
    asm volatile("s_waitcnt lgkmcnt(0)" ::: "memory");
    wg_barrier();

#pragma unroll
    for (int m = 0; m < 4; ++m)
#pragma unroll
        for (int j = 0; j < 4; ++j) {
            const int row = m * 16 + fq * 4 + j;
            const float rinv = 1.0f / (rs[row] + rs[64 + row] + rs[128 + row] + rs[192 + row]);
#pragma unroll
            for (int n = 0; n < 4; ++n) {
                const int d = wid * 64 + n * 16 + fr;
                Og[(long)(qb * 64 + row) * HEAD_ALL + h * EMB + d] = f2b(oacc[m][n][j] * rinv);
            }
        }
}

// ---------------- split-K reduce + bias: out = sum_s part[s] + bias ----------------
__global__ void reduce_bias(const float* __restrict__ part, const float* __restrict__ bias,
                            float* __restrict__ out) {
    const int i = blockIdx.x * 256 + threadIdx.x;
    const long stride4 = (long)T_SEQ * EMB / 4;
    const f32x4* p = (const f32x4*)part;
    f32x4 s = p[i];
#pragma unroll
    for (int sl = 1; sl < 8; ++sl) s += p[i + sl * stride4];
    f32x4 b = *(const f32x4*)(bias + ((i * 4) % EMB));
    *((f32x4*)out + i) = s + b;
}

extern "C" void kernel_launch(void* const* d_in, const int* in_sizes, int n_in,
                              void* d_out, int out_size, void* d_ws, size_t ws_size,
                              hipStream_t stream)
{
    const float* x  = (const float*)d_in[0];
    const float* y  = (const float*)d_in[1];
    const float* Wk = (const float*)d_in[2];
    const float* Wq = (const float*)d_in[3];
    const float* Wv = (const float*)d_in[4];
    const float* Wu = (const float*)d_in[5];
    const float* bu = (const float*)d_in[6];
    char* ws = (char*)d_ws;
    const size_t MB = 1024ull * 1024ull;

    // Workspace layout (r7 offsets kept)
    unsigned short* xb   = (unsigned short*)(ws + 0);        // 2 MB  [transient]
    unsigned short* yb   = (unsigned short*)(ws + 2 * MB);   // 2 MB  [transient]
    unsigned short* WT3  = (unsigned short*)(ws + 4 * MB);   // 12 MB: WvT,WkT,WqT [transient]
    unsigned short* PRJ  = (unsigned short*)(ws + 48 * MB);  // Vb@48 [transient], Kb@64, Qb@80
    unsigned short* Vb   = (unsigned short*)(ws + 48 * MB);
    unsigned short* Kb   = (unsigned short*)(ws + 64 * MB);
    unsigned short* Qb   = (unsigned short*)(ws + 80 * MB);
    unsigned short* WuT  = (unsigned short*)(ws + 96 * MB);  // 4 MB
    unsigned short* VTb  = (unsigned short*)(ws + 100 * MB); // 16 MB
    unsigned short* Ob   = (unsigned short*)(ws + 116 * MB); // 16 MB
    float*          part = (float*)(ws + 0);                 // 32 MB f32

    const float scale2 = 0.04419417382415922f;  // 512^-0.5
    const long TE = (long)T_SEQ * EMB;

    // 1) converts
    cvt_bf16_2<<<dim3(512, 2), dim3(256), 0, stream>>>(x, y, xb, yb, T_SEQ * EMB / 8);
    transpose_cvt3_f32<<<dim3(HEAD_ALL / 64, EMB / 64, 3), dim3(256), 0, stream>>>(
        Wv, Wk, Wq, WT3, EMB, HEAD_ALL, (long)2 * MB);
    transpose_cvt3_f32<<<dim3(EMB / 64, HEAD_ALL / 64, 1), dim3(256), 0, stream>>>(
        Wu, nullptr, nullptr, WuT, HEAD_ALL, EMB, 0);

    // 2) fused projections -> [3][h][t][e] bf16 at PRJ (batch0=V(x), 1=K(x), 2=Q(y))
    gemm8p<256, 256, 8, 1><<<dim3(HEAD_ALL / 256, T_SEQ / 256, 3), 512, 0, stream>>>(
        xb, yb, WT3, PRJ, EMB, 1.f, 0, (long)2 * MB, (long)8 * MB, 0);

    // 3) V -> V^T per head
    transpose_bf16<<<dim3(EMB / 64, T_SEQ / 64, NH), dim3(256), 0, stream>>>(
        Vb, VTb, T_SEQ, EMB, TE, TE);

    // 4) fused attention: O = softmax(QK^T * s) @ V  (no-max softmax, fused)
    attn_fused<<<dim3(32, 8), 512, 0, stream>>>(Qb, Kb, VTb, Ob, scale2);

    // 5) split-K=8 final GEMM: part[s] = O @ Wu over K-slice s (K=512 each)
    gemm8p<256, 128, 8, 3><<<dim3(EMB / 128, T_SEQ / 256, 8), 512, 0, stream>>>(
        Ob, nullptr, WuT, part, HEAD_ALL, 1.f, 0, 0, 0, EMB);

    // 6) out = sum(part) + bias, f32
    reduce_bias<<<dim3(T_SEQ * EMB / 4 / 256), dim3(256), 0, stream>>>(part, bu, (float*)d_out);
}

// Round 10
// 277.697 us; speedup vs baseline: 1.0003x; 1.0003x over previous
//
#include <hip/hip_runtime.h>
#include <hip/hip_bf16.h>
#include <stdint.h>

#define T_SEQ 2048
#define EMB   512
#define NH    8
#define HEAD_ALL 4096   // NH*EMB

typedef __attribute__((ext_vector_type(8))) short short8;
typedef __attribute__((ext_vector_type(4))) float f32x4;

__device__ __forceinline__ unsigned short f2b(float f) {
    __hip_bfloat16 h = __float2bfloat16(f);
    return *reinterpret_cast<unsigned short*>(&h);
}
__device__ __forceinline__ float b2f(unsigned short u) {
    return __uint_as_float(((unsigned)u) << 16);
}
__device__ __forceinline__ void gload_lds16(const void* g, void* l) {
    __builtin_amdgcn_global_load_lds((__attribute__((address_space(1))) void*)(void*)(g),
                                     (__attribute__((address_space(3))) void*)(l), 16, 0, 0);
}
__device__ __forceinline__ void wg_barrier() {
    asm volatile("" ::: "memory");
    __builtin_amdgcn_s_barrier();
    asm volatile("" ::: "memory");
}

// ---------------- f32 -> bf16 convert, two tensors in one launch ----------------
__global__ void cvt_bf16_2(const float* __restrict__ a, const float* __restrict__ b,
                           unsigned short* __restrict__ oa, unsigned short* __restrict__ ob, int n8) {
    const float* in = blockIdx.y ? b : a;
    unsigned short* out = blockIdx.y ? ob : oa;
    int i = blockIdx.x * 256 + threadIdx.x;
    if (i >= n8) return;
    const f32x4* p = (const f32x4*)in + 2 * (size_t)i;
    f32x4 va = p[0], vb = p[1];
    uint4 o;
    o.x = (unsigned)f2b(va[0]) | ((unsigned)f2b(va[1]) << 16);
    o.y = (unsigned)f2b(va[2]) | ((unsigned)f2b(va[3]) << 16);
    o.z = (unsigned)f2b(vb[0]) | ((unsigned)f2b(vb[1]) << 16);
    o.w = (unsigned)f2b(vb[2]) | ((unsigned)f2b(vb[3]) << 16);
    *((uint4*)out + i) = o;
}

// ------- f32 [R][C] -> bf16 [C][R] transpose-convert, z selects source -------
__global__ void transpose_cvt3_f32(const float* __restrict__ w0, const float* __restrict__ w1,
                                   const float* __restrict__ w2, unsigned short* __restrict__ out,
                                   int R, int C, long outS) {
    __shared__ unsigned short t[64][66];
    const int z = blockIdx.z;
    const float* in = (z == 0) ? w0 : ((z == 1) ? w1 : w2);
    unsigned short* ob = out + (long)z * outS;
    const int tid = threadIdx.x;
    const int r0 = blockIdx.y * 64, c0 = blockIdx.x * 64;
#pragma unroll
    for (int it = 0; it < 4; ++it) {
        int flat = it * 256 + tid;
        int r = flat >> 4, c4 = flat & 15;
        f32x4 v = *(const f32x4*)(in + (long)(r0 + r) * C + c0 + c4 * 4);
#pragma unroll
        for (int w = 0; w < 4; ++w) t[r][c4 * 4 + w] = f2b(v[w]);
    }
    __syncthreads();
#pragma unroll
    for (int it = 0; it < 2; ++it) {
        int flat = it * 256 + tid;
        int rr = flat >> 3, c8 = flat & 7;
        unsigned u[4];
#pragma unroll
        for (int w = 0; w < 4; ++w) {
            unsigned short a = t[c8 * 8 + 2 * w][rr];
            unsigned short b = t[c8 * 8 + 2 * w + 1][rr];
            u[w] = (unsigned)a | ((unsigned)b << 16);
        }
        *(uint4*)(ob + (long)(c0 + rr) * R + r0 + c8 * 8) = make_uint4(u[0], u[1], u[2], u[3]);
    }
}

// ---------------- bf16 [R][C] -> bf16 [C][R] transpose, batched ----------------
__global__ void transpose_bf16(const unsigned short* __restrict__ in, unsigned short* __restrict__ out,
                               int R, int C, long inS, long outS) {
    __shared__ unsigned short t[64][66];
    const unsigned short* ib = in + (long)blockIdx.z * inS;
    unsigned short* ob = out + (long)blockIdx.z * outS;
    const int tid = threadIdx.x;
    const int r0 = blockIdx.y * 64, c0 = blockIdx.x * 64;
#pragma unroll
    for (int it = 0; it < 2; ++it) {
        int flat = it * 256 + tid;
        int r = flat >> 3, c8 = flat & 7;
        uint4 v = *(const uint4*)(ib + (long)(r0 + r) * C + c0 + c8 * 8);
        unsigned u[4] = {v.x, v.y, v.z, v.w};
#pragma unroll
        for (int w = 0; w < 4; ++w) {
            t[r][c8 * 8 + 2 * w]     = (unsigned short)(u[w] & 0xffff);
            t[r][c8 * 8 + 2 * w + 1] = (unsigned short)(u[w] >> 16);
        }
    }
    __syncthreads();
#pragma unroll
    for (int it = 0; it < 2; ++it) {
        int flat = it * 256 + tid;
        int rr = flat >> 3, c8 = flat & 7;
        unsigned u[4];
#pragma unroll
        for (int w = 0; w < 4; ++w)
            u[w] = (unsigned)t[c8 * 8 + 2 * w][rr] | ((unsigned)t[c8 * 8 + 2 * w + 1][rr] << 16);
        *(uint4*)(ob + (long)(c0 + rr) * R + r0 + c8 * 8) = make_uint4(u[0], u[1], u[2], u[3]);
    }
}

// ============== 8-phase double-buffered GEMM (proven; used for proj + final) ==============
template<int R_>
__device__ __forceinline__ void stage2(const unsigned short* __restrict__ src, int kfull,
                                       short* ldsbase, int i, int tid, int wid) {
#pragma unroll
    for (int s = 0; s < 2; ++s) {
        const int ii = i + s;
        const int r = ii * 64 + (tid >> 3);
        const int d = (tid & 7) * 16;                  // dest byte within 128B row
        const int sc = (d ^ ((r & 7) << 4)) >> 1;      // inverse-swizzled src col (elems)
        gload_lds16(src + (long)r * kfull + sc, ldsbase + ii * 4096 + wid * 512);
    }
}

// MODE 1: projections -> head-split bf16 [h][t][e]: batch0=V(x), 1=K(x), 2=Q(y)
// MODE 3: f32 split-K partial over K-slice batch
template<int BM, int BN, int KTILES, int MODE>
__global__ __launch_bounds__(512, 2)
void gemm8p(const unsigned short* __restrict__ A, const unsigned short* __restrict__ A2,
            const unsigned short* __restrict__ B, void* __restrict__ Cout,
            int kfull, float alpha, long As, long Bs, long Cs, int ldc)
{
    static_assert(KTILES >= 3, "pipeline needs >=3 K-tiles");
    constexpr int ATILE = BM * 64;
    constexpr int BTILE = BN * 64;
    constexpr int LA = BM / 64;
    constexpr int LB = BN / 64;
    constexpr int MF = BM / 32;
    constexpr int NF = BN / 64;
    constexpr int MFP = MF / 4;

    __shared__ __align__(16) short lds[2 * (ATILE + BTILE)];

    const int tid = threadIdx.x;
    const int wid = tid >> 6, lane = tid & 63;
    const int wm = wid >> 2, wn = wid & 3;
    const int fr = lane & 15, fq = lane >> 4;

    // T1: XCD chunk swizzle
    const int nwg = gridDim.x * gridDim.y * gridDim.z;
    int flat = blockIdx.x + gridDim.x * (blockIdx.y + gridDim.y * blockIdx.z);
    flat = (flat & 7) * (nwg >> 3) + (flat >> 3);
    const int bx = flat % gridDim.x;
    const int rem = flat / gridDim.x;
    const int by = rem % gridDim.y;
    const long batch = rem / gridDim.y;

    const int bm = by * BM, bn = bx * BN;

    const unsigned short* Ab;
    const unsigned short* Bb;
    int koff = 0;
    if constexpr (MODE == 1) { Ab = (batch == 2) ? A2 : A; Bb = B + batch * Bs; }
    else { Ab = A; Bb = B; koff = (int)batch * (KTILES * 64); }

    const unsigned short* Ag = Ab + (long)bm * kfull + koff;
    const unsigned short* Bg = Bb + (long)bn * kfull + koff;

    f32x4 acc[MF][NF];
#pragma unroll
    for (int i = 0; i < MF; i++)
#pragma unroll
        for (int j = 0; j < NF; j++) acc[i][j] = 0.f;

#pragma unroll
    for (int i = 0; i < LA; i += 2) stage2<BM>(Ag, kfull, lds, i, tid, wid);
#pragma unroll
    for (int i = 0; i < LB; i += 2) stage2<BN>(Bg, kfull, lds + 2 * ATILE, i, tid, wid);
#pragma unroll
    for (int i = 0; i < LB; i += 2) stage2<BN>(Bg + 64, kfull, lds + 2 * ATILE + BTILE, i, tid, wid);
    if constexpr (LB == 4) asm volatile("s_waitcnt vmcnt(4)" ::: "memory");
    else                   asm volatile("s_waitcnt vmcnt(2)" ::: "memory");
    wg_barrier();

#pragma unroll 2
    for (int t = 0; t < KTILES; ++t) {
        short* la  = lds + (t & 1) * ATILE;
        short* laN = lds + ((t + 1) & 1) * ATILE;
        short* lb  = lds + 2 * ATILE + (t & 1) * BTILE;
        const int kA = (t + 1) * 64;
        const int kB = (t + 2) * 64;

        short8 bfrag[NF][2];
#pragma unroll
        for (int q = 0; q < 4; ++q) {
            if (q == 0) {
#pragma unroll
                for (int nf = 0; nf < NF; ++nf)
#pragma unroll
                    for (int kk = 0; kk < 2; ++kk) {
                        const int r = wn * (BN / 4) + nf * 16 + fr;
                        const int cb = kk * 64 + fq * 16;
                        bfrag[nf][kk] = *(const short8*)(lb + r * 64 + ((cb ^ ((r & 7) << 4)) >> 1));
                    }
            }
            short8 afrag[MFP][2];
#pragma unroll
            for (int mf = 0; mf < MFP; ++mf)
#pragma unroll
                for (int kk = 0; kk < 2; ++kk) {
                    const int r = wm * (BM / 2) + q * (BM / 8) + mf * 16 + fr;
                    const int cb = kk * 64 + fq * 16;
                    afrag[mf][kk] = *(const short8*)(la + r * 64 + ((cb ^ ((r & 7) << 4)) >> 1));
                }
            if (t + 1 < KTILES) {
                if (q == 0) stage2<BM>(Ag + kA, kfull, laN, 0, tid, wid);
                if (q == 1 && LA == 4) stage2<BM>(Ag + kA, kfull, laN, 2, tid, wid);
            }
            if (t + 2 < KTILES) {
                if (q == 2) stage2<BN>(Bg + kB, kfull, lb, 0, tid, wid);
                if (q == 3 && LB == 4) stage2<BN>(Bg + kB, kfull, lb, 2, tid, wid);
            }
            wg_barrier();
            __builtin_amdgcn_s_setprio(1);
#pragma unroll
            for (int mf = 0; mf < MFP; ++mf)
#pragma unroll
                for (int nf = 0; nf < NF; ++nf)
#pragma unroll
                    for (int kk = 0; kk < 2; ++kk)
                        acc[q * MFP + mf][nf] = __builtin_amdgcn_mfma_f32_16x16x32_bf16(
                            afrag[mf][kk], bfrag[nf][kk], acc[q * MFP + mf][nf], 0, 0, 0);
            __builtin_amdgcn_s_setprio(0);
            if (q == 3) {
                if (t + 2 < KTILES) {
                    if constexpr (LB == 4) asm volatile("s_waitcnt vmcnt(4)" ::: "memory");
                    else                   asm volatile("s_waitcnt vmcnt(2)" ::: "memory");
                } else {
                    asm volatile("s_waitcnt vmcnt(0)" ::: "memory");
                }
            }
            wg_barrier();
        }
    }

#pragma unroll
    for (int m = 0; m < MF; ++m)
#pragma unroll
        for (int j = 0; j < 4; ++j) {
            const int row = bm + wm * (BM / 2) + m * 16 + fq * 4 + j;
#pragma unroll
            for (int n = 0; n < NF; ++n) {
                const int col = bn + wn * (BN / 4) + n * 16 + fr;
                const float v = acc[m][n][j] * alpha;
                if constexpr (MODE == 1) {
                    unsigned short* C = (unsigned short*)Cout + batch * Cs;
                    C[(long)(col >> 9) * ((long)T_SEQ * EMB) + (long)row * EMB + (col & 511)] = f2b(v);
                } else {
                    float* C = (float*)Cout + batch * ((long)T_SEQ * EMB);
                    C[(long)row * ldc + col] = v;
                }
            }
        }
}

// ============== fused attention: O = (exp(s*QK^T) @ V) / rowsum ==============
// Block = 64 q-rows x 1 head; 8 waves; grid (32 qb, 8 h), head-per-XCD swizzle.
// LDS 140 KB -> HW occupancy is 1 block/CU regardless, so declare min_blocks=1
// and get the full 256-VGPR budget (r9's (512,2) capped at 128 -> scratch spill:
// FETCH 24.6->90.6 MB. This round's single change.)
// LDS: K[64kv][512e] @0 (64KB, swz (kv&7)<<4 per 1024B row),
//      VT[512d][64kv] @65536 (64KB, swz (d&7)<<4 per 128B row),
//      St[64q][64kv] bf16 @131072 (8KB, swz2 = ((q&7)<<4)^((q&8)<<2) per 128B row),
//      rs[4][64] f32 @139264.
// QK waves (rg=wid&1, ch=wid>>1): rows rg*32..+32 (2 m-frags, Q in 128 VGPRs),
//     kv cols ch*16..+16: each K-frag read ONCE per ks, shared by both m-frags.
// PV: wave owns d-slice wid*64..+64: 4m x 4n frags x 2 ksteps from St + VT.
// Pipeline: vmcnt(8) @top (K_t ready, VT_t in flight); vmcnt(0) pre-PV;
// stage K_{t+1} after B2 (K_t reads retired); stage VT_{t+1} after B3.
__global__ __launch_bounds__(512, 1)
void attn_fused(const unsigned short* __restrict__ Qg, const unsigned short* __restrict__ Kg,
                const unsigned short* __restrict__ VTg, unsigned short* __restrict__ Og,
                float scale)
{
    __shared__ __align__(16) short lds[70144];   // 140288 B
    float* rs = (float*)(lds + 69632);           // [4][64] @byte 139264
    char* ldsb = (char*)lds;

    const int tid = threadIdx.x;
    const int wid = tid >> 6, lane = tid & 63;
    const int fr = lane & 15, fq = lane >> 4;
    const int rg = wid & 1, ch = wid >> 1;       // QK role: 32 q-rows, 16 kv-cols

    // head-per-XCD: orig%8 = XCD (round-robin dispatch) -> head = f>>5
    const int orig = blockIdx.x + 32 * blockIdx.y;
    const int f = (orig & 7) * 32 + (orig >> 3);
    const int qb = f & 31, h = f >> 5;
    const long TE = (long)T_SEQ * EMB;
    const unsigned short* Qh = Qg + (long)h * TE + (long)(qb * 64) * EMB;
    const unsigned short* Kh = Kg + (long)h * TE;
    const unsigned short* Vh = VTg + (long)h * TE;

    // Q fragments in registers: 2 m-frags, rows rg*32 + mm*16 + fr, k = ks*32 + fq*8
    short8 qreg[2][16];
#pragma unroll
    for (int mm = 0; mm < 2; ++mm)
#pragma unroll
        for (int ks = 0; ks < 16; ++ks)
            qreg[mm][ks] = *(const short8*)(Qh + (long)(rg * 32 + mm * 16 + fr) * EMB + ks * 32 + fq * 8);

    // ---- staging (dest = wave-uniform base; HW adds lane*16) ----
    auto stageK = [&](int kb) {
#pragma unroll
        for (int it = 0; it < 8; ++it) {
            const int c = it * 512 + tid;
            const int kv = c >> 6, s = c & 63;
            gload_lds16(Kh + (long)(kb * 64 + kv) * EMB + (((s * 16) ^ ((kv & 7) << 4)) >> 1),
                        lds + (it * 512 + wid * 64) * 8);
        }
    };
    auto stageV = [&](int kb) {
#pragma unroll
        for (int it = 0; it < 8; ++it) {
            const int c = it * 512 + tid;
            const int d = c >> 3, s = c & 7;
            gload_lds16(Vh + (long)d * T_SEQ + kb * 64 + (((s * 16) ^ ((d & 7) << 4)) >> 1),
                        lds + 32768 + (it * 512 + wid * 64) * 8);
        }
    };

    f32x4 oacc[4][4];
#pragma unroll
    for (int m = 0; m < 4; ++m)
#pragma unroll
        for (int n = 0; n < 4; ++n) oacc[m][n] = 0.f;
    float rsum[2][4];
#pragma unroll
    for (int mm = 0; mm < 2; ++mm)
#pragma unroll
        for (int j = 0; j < 4; ++j) rsum[mm][j] = 0.f;

    stageK(0);
    stageV(0);

#pragma unroll 1
    for (int t = 0; t < 32; ++t) {
        asm volatile("s_waitcnt vmcnt(8)" ::: "memory");   // K_t landed
        wg_barrier();                                       // B1: K_t visible

        // ---- QK^T: one B-frag per ks, used by both m-frags; 2 k-split accs ----
        f32x4 sacc[2][2];
#pragma unroll
        for (int mm = 0; mm < 2; ++mm) { sacc[mm][0] = 0.f; sacc[mm][1] = 0.f; }
        const int kv = ch * 16 + fr;
#pragma unroll
        for (int ks = 0; ks < 16; ++ks) {
            const short8 bfr = *(const short8*)(ldsb + kv * 1024 +
                                ((ks * 64 + fq * 16) ^ ((kv & 7) << 4)));
#pragma unroll
            for (int mm = 0; mm < 2; ++mm)
                sacc[mm][ks & 1] = __builtin_amdgcn_mfma_f32_16x16x32_bf16(
                    qreg[mm][ks], bfr, sacc[mm][ks & 1], 0, 0, 0);
        }
        // ---- exp + rowsum + S~ -> LDS (swz2: disjoint 32B regions per fq-group) ----
#pragma unroll
        for (int mm = 0; mm < 2; ++mm)
#pragma unroll
            for (int j = 0; j < 4; ++j) {
                const float v = __expf(scale * (sacc[mm][0][j] + sacc[mm][1][j]));
                rsum[mm][j] += v;
                const int row = rg * 32 + mm * 16 + fq * 4 + j;
                *(unsigned short*)(ldsb + 131072 + row * 128 +
                    ((kv * 2) ^ ((row & 7) << 4) ^ ((row & 8) << 2))) = f2b(v);
            }
        asm volatile("s_waitcnt lgkmcnt(0)" ::: "memory");
        asm volatile("s_waitcnt vmcnt(0)" ::: "memory");    // VT_t landed
        wg_barrier();                                        // B2: S~ + VT_t visible; K_t reads retired
        if (t + 1 < 32) stageK(t + 1);

        // ---- PV: O[64 x 64(d-slice)] += S~ @ V ----
#pragma unroll
        for (int kk = 0; kk < 2; ++kk) {
            short8 sa[4], vb[4];
#pragma unroll
            for (int m = 0; m < 4; ++m) {
                const int row = m * 16 + fr;
                sa[m] = *(const short8*)(ldsb + 131072 + row * 128 +
                          ((kk * 64 + fq * 16) ^ ((row & 7) << 4) ^ ((row & 8) << 2)));
            }
#pragma unroll
            for (int n = 0; n < 4; ++n) {
                const int d = wid * 64 + n * 16 + fr;
                vb[n] = *(const short8*)(ldsb + 65536 + d * 128 +
                          ((kk * 64 + fq * 16) ^ ((d & 7) << 4)));
            }
            __builtin_amdgcn_s_setprio(1);
#pragma unroll
            for (int m = 0; m < 4; ++m)
#pragma unroll
                for (int n = 0; n < 4; ++n)
                    oacc[m][n] = __builtin_amdgcn_mfma_f32_16x16x32_bf16(
                        sa[m], vb[n], oacc[m][n], 0, 0, 0);
            __builtin_amdgcn_s_setprio(0);
        }
        wg_barrier();                                        // B3: VT_t + S~ reads retired
        if (t + 1 < 32) stageV(t + 1);
    }

    // ---- rowsum reduce: per-wave kv-slice sums -> rs[ch][row]; combine 4 slices ----
#pragma unroll
    for (int mm = 0; mm < 2; ++mm)
#pragma unroll
        for (int j = 0; j < 4; ++j) {
            float v = rsum[mm][j];
            v += __shfl_xor(v, 1);
            v += __shfl_xor(v, 2);
            v += __shfl_xor(v, 4);
            v += __shfl_xor(v, 8);
            if (fr == 0) rs[ch * 64 + rg * 32 + mm * 16 + fq * 4 + j] = v;
        }
    asm volatile("s_waitcnt lgkmcnt(0)" ::: "memory");
    wg_barrier();

#pragma unroll
    for (int m = 0; m < 4; ++m)
#pragma unroll
        for (int j = 0; j < 4; ++j) {
            const int row = m * 16 + fq * 4 + j;
            const float rinv = 1.0f / (rs[row] + rs[64 + row] + rs[128 + row] + rs[192 + row]);
#pragma unroll
            for (int n = 0; n < 4; ++n) {
                const int d = wid * 64 + n * 16 + fr;
                Og[(long)(qb * 64 + row) * HEAD_ALL + h * EMB + d] = f2b(oacc[m][n][j] * rinv);
            }
        }
}

// ---------------- split-K reduce + bias: out = sum_s part[s] + bias ----------------
__global__ void reduce_bias(const float* __restrict__ part, const float* __restrict__ bias,
                            float* __restrict__ out) {
    const int i = blockIdx.x * 256 + threadIdx.x;
    const long stride4 = (long)T_SEQ * EMB / 4;
    const f32x4* p = (const f32x4*)part;
    f32x4 s = p[i];
#pragma unroll
    for (int sl = 1; sl < 8; ++sl) s += p[i + sl * stride4];
    f32x4 b = *(const f32x4*)(bias + ((i * 4) % EMB));
    *((f32x4*)out + i) = s + b;
}

extern "C" void kernel_launch(void* const* d_in, const int* in_sizes, int n_in,
                              void* d_out, int out_size, void* d_ws, size_t ws_size,
                              hipStream_t stream)
{
    const float* x  = (const float*)d_in[0];
    const float* y  = (const float*)d_in[1];
    const float* Wk = (const float*)d_in[2];
    const float* Wq = (const float*)d_in[3];
    const float* Wv = (const float*)d_in[4];
    const float* Wu = (const float*)d_in[5];
    const float* bu = (const float*)d_in[6];
    char* ws = (char*)d_ws;
    const size_t MB = 1024ull * 1024ull;

    // Workspace layout (r7 offsets kept)
    unsigned short* xb   = (unsigned short*)(ws + 0);        // 2 MB  [transient]
    unsigned short* yb   = (unsigned short*)(ws + 2 * MB);   // 2 MB  [transient]
    unsigned short* WT3  = (unsigned short*)(ws + 4 * MB);   // 12 MB: WvT,WkT,WqT [transient]
    unsigned short* PRJ  = (unsigned short*)(ws + 48 * MB);  // Vb@48 [transient], Kb@64, Qb@80
    unsigned short* Vb   = (unsigned short*)(ws + 48 * MB);
    unsigned short* Kb   = (unsigned short*)(ws + 64 * MB);
    unsigned short* Qb   = (unsigned short*)(ws + 80 * MB);
    unsigned short* WuT  = (unsigned short*)(ws + 96 * MB);  // 4 MB
    unsigned short* VTb  = (unsigned short*)(ws + 100 * MB); // 16 MB
    unsigned short* Ob   = (unsigned short*)(ws + 116 * MB); // 16 MB
    float*          part = (float*)(ws + 0);                 // 32 MB f32

    const float scale2 = 0.04419417382415922f;  // 512^-0.5
    const long TE = (long)T_SEQ * EMB;

    // 1) converts
    cvt_bf16_2<<<dim3(512, 2), dim3(256), 0, stream>>>(x, y, xb, yb, T_SEQ * EMB / 8);
    transpose_cvt3_f32<<<dim3(HEAD_ALL / 64, EMB / 64, 3), dim3(256), 0, stream>>>(
        Wv, Wk, Wq, WT3, EMB, HEAD_ALL, (long)2 * MB);
    transpose_cvt3_f32<<<dim3(EMB / 64, HEAD_ALL / 64, 1), dim3(256), 0, stream>>>(
        Wu, nullptr, nullptr, WuT, HEAD_ALL, EMB, 0);

    // 2) fused projections -> [3][h][t][e] bf16 at PRJ (batch0=V(x), 1=K(x), 2=Q(y))
    gemm8p<256, 256, 8, 1><<<dim3(HEAD_ALL / 256, T_SEQ / 256, 3), 512, 0, stream>>>(
        xb, yb, WT3, PRJ, EMB, 1.f, 0, (long)2 * MB, (long)8 * MB, 0);

    // 3) V -> V^T per head
    transpose_bf16<<<dim3(EMB / 64, T_SEQ / 64, NH), dim3(256), 0, stream>>>(
        Vb, VTb, T_SEQ, EMB, TE, TE);

    // 4) fused attention: O = softmax(QK^T * s) @ V  (no-max softmax, fused)
    attn_fused<<<dim3(32, 8), 512, 0, stream>>>(Qb, Kb, VTb, Ob, scale2);

    // 5) split-K=8 final GEMM: part[s] = O @ Wu over K-slice s (K=512 each)
    gemm8p<256, 128, 8, 3><<<dim3(EMB / 128, T_SEQ / 256, 8), 512, 0, stream>>>(
        Ob, nullptr, WuT, part, HEAD_ALL, 1.f, 0, 0, 0, EMB);

    // 6) out = sum(part) + bias, f32
    reduce_bias<<<dim3(T_SEQ * EMB / 4 / 256), dim3(256), 0, stream>>>(part, bu, (float*)d_out);
}

// Round 11
// 181.130 us; speedup vs baseline: 1.5336x; 1.5331x over previous
//
#include <hip/hip_runtime.h>
#include <hip/hip_bf16.h>
#include <stdint.h>

#define T_SEQ 2048
#define EMB   512
#define NH    8
#define HEAD_ALL 4096   // NH*EMB

typedef __attribute__((ext_vector_type(8))) short short8;
typedef __attribute__((ext_vector_type(4))) float f32x4;

__device__ __forceinline__ unsigned short f2b(float f) {
    __hip_bfloat16 h = __float2bfloat16(f);
    return *reinterpret_cast<unsigned short*>(&h);
}
__device__ __forceinline__ float b2f(unsigned short u) {
    return __uint_as_float(((unsigned)u) << 16);
}
__device__ __forceinline__ void gload_lds16(const void* g, void* l) {
    __builtin_amdgcn_global_load_lds((__attribute__((address_space(1))) void*)(void*)(g),
                                     (__attribute__((address_space(3))) void*)(l), 16, 0, 0);
}
__device__ __forceinline__ void wg_barrier() {
    asm volatile("" ::: "memory");
    __builtin_amdgcn_s_barrier();
    asm volatile("" ::: "memory");
}

// ---------------- f32 -> bf16 convert, two tensors in one launch ----------------
__global__ void cvt_bf16_2(const float* __restrict__ a, const float* __restrict__ b,
                           unsigned short* __restrict__ oa, unsigned short* __restrict__ ob, int n8) {
    const float* in = blockIdx.y ? b : a;
    unsigned short* out = blockIdx.y ? ob : oa;
    int i = blockIdx.x * 256 + threadIdx.x;
    if (i >= n8) return;
    const f32x4* p = (const f32x4*)in + 2 * (size_t)i;
    f32x4 va = p[0], vb = p[1];
    uint4 o;
    o.x = (unsigned)f2b(va[0]) | ((unsigned)f2b(va[1]) << 16);
    o.y = (unsigned)f2b(va[2]) | ((unsigned)f2b(va[3]) << 16);
    o.z = (unsigned)f2b(vb[0]) | ((unsigned)f2b(vb[1]) << 16);
    o.w = (unsigned)f2b(vb[2]) | ((unsigned)f2b(vb[3]) << 16);
    *((uint4*)out + i) = o;
}

// ------- f32 [R][C] -> bf16 [C][R] transpose-convert, z selects source -------
__global__ void transpose_cvt3_f32(const float* __restrict__ w0, const float* __restrict__ w1,
                                   const float* __restrict__ w2, unsigned short* __restrict__ out,
                                   int R, int C, long outS) {
    __shared__ unsigned short t[64][66];
    const int z = blockIdx.z;
    const float* in = (z == 0) ? w0 : ((z == 1) ? w1 : w2);
    unsigned short* ob = out + (long)z * outS;
    const int tid = threadIdx.x;
    const int r0 = blockIdx.y * 64, c0 = blockIdx.x * 64;
#pragma unroll
    for (int it = 0; it < 4; ++it) {
        int flat = it * 256 + tid;
        int r = flat >> 4, c4 = flat & 15;
        f32x4 v = *(const f32x4*)(in + (long)(r0 + r) * C + c0 + c4 * 4);
#pragma unroll
        for (int w = 0; w < 4; ++w) t[r][c4 * 4 + w] = f2b(v[w]);
    }
    __syncthreads();
#pragma unroll
    for (int it = 0; it < 2; ++it) {
        int flat = it * 256 + tid;
        int rr = flat >> 3, c8 = flat & 7;
        unsigned u[4];
#pragma unroll
        for (int w = 0; w < 4; ++w) {
            unsigned short a = t[c8 * 8 + 2 * w][rr];
            unsigned short b = t[c8 * 8 + 2 * w + 1][rr];
            u[w] = (unsigned)a | ((unsigned)b << 16);
        }
        *(uint4*)(ob + (long)(c0 + rr) * R + r0 + c8 * 8) = make_uint4(u[0], u[1], u[2], u[3]);
    }
}

// ---------------- bf16 [R][C] -> bf16 [C][R] transpose, batched ----------------
__global__ void transpose_bf16(const unsigned short* __restrict__ in, unsigned short* __restrict__ out,
                               int R, int C, long inS, long outS) {
    __shared__ unsigned short t[64][66];
    const unsigned short* ib = in + (long)blockIdx.z * inS;
    unsigned short* ob = out + (long)blockIdx.z * outS;
    const int tid = threadIdx.x;
    const int r0 = blockIdx.y * 64, c0 = blockIdx.x * 64;
#pragma unroll
    for (int it = 0; it < 2; ++it) {
        int flat = it * 256 + tid;
        int r = flat >> 3, c8 = flat & 7;
        uint4 v = *(const uint4*)(ib + (long)(r0 + r) * C + c0 + c8 * 8);
        unsigned u[4] = {v.x, v.y, v.z, v.w};
#pragma unroll
        for (int w = 0; w < 4; ++w) {
            t[r][c8 * 8 + 2 * w]     = (unsigned short)(u[w] & 0xffff);
            t[r][c8 * 8 + 2 * w + 1] = (unsigned short)(u[w] >> 16);
        }
    }
    __syncthreads();
#pragma unroll
    for (int it = 0; it < 2; ++it) {
        int flat = it * 256 + tid;
        int rr = flat >> 3, c8 = flat & 7;
        unsigned u[4];
#pragma unroll
        for (int w = 0; w < 4; ++w)
            u[w] = (unsigned)t[c8 * 8 + 2 * w][rr] | ((unsigned)t[c8 * 8 + 2 * w + 1][rr] << 16);
        *(uint4*)(ob + (long)(c0 + rr) * R + r0 + c8 * 8) = make_uint4(u[0], u[1], u[2], u[3]);
    }
}

// ============== 8-phase double-buffered GEMM (proven; used for proj + final) ==============
template<int R_>
__device__ __forceinline__ void stage2(const unsigned short* __restrict__ src, int kfull,
                                       short* ldsbase, int i, int tid, int wid) {
#pragma unroll
    for (int s = 0; s < 2; ++s) {
        const int ii = i + s;
        const int r = ii * 64 + (tid >> 3);
        const int d = (tid & 7) * 16;                  // dest byte within 128B row
        const int sc = (d ^ ((r & 7) << 4)) >> 1;      // inverse-swizzled src col (elems)
        gload_lds16(src + (long)r * kfull + sc, ldsbase + ii * 4096 + wid * 512);
    }
}

// MODE 1: projections -> head-split bf16 [h][t][e]: batch0=V(x), 1=K(x), 2=Q(y)
// MODE 3: f32 split-K partial over K-slice batch
template<int BM, int BN, int KTILES, int MODE>
__global__ __launch_bounds__(512, 2)
void gemm8p(const unsigned short* __restrict__ A, const unsigned short* __restrict__ A2,
            const unsigned short* __restrict__ B, void* __restrict__ Cout,
            int kfull, float alpha, long As, long Bs, long Cs, int ldc)
{
    static_assert(KTILES >= 3, "pipeline needs >=3 K-tiles");
    constexpr int ATILE = BM * 64;
    constexpr int BTILE = BN * 64;
    constexpr int LA = BM / 64;
    constexpr int LB = BN / 64;
    constexpr int MF = BM / 32;
    constexpr int NF = BN / 64;
    constexpr int MFP = MF / 4;

    __shared__ __align__(16) short lds[2 * (ATILE + BTILE)];

    const int tid = threadIdx.x;
    const int wid = tid >> 6, lane = tid & 63;
    const int wm = wid >> 2, wn = wid & 3;
    const int fr = lane & 15, fq = lane >> 4;

    // T1: XCD chunk swizzle
    const int nwg = gridDim.x * gridDim.y * gridDim.z;
    int flat = blockIdx.x + gridDim.x * (blockIdx.y + gridDim.y * blockIdx.z);
    flat = (flat & 7) * (nwg >> 3) + (flat >> 3);
    const int bx = flat % gridDim.x;
    const int rem = flat / gridDim.x;
    const int by = rem % gridDim.y;
    const long batch = rem / gridDim.y;

    const int bm = by * BM, bn = bx * BN;

    const unsigned short* Ab;
    const unsigned short* Bb;
    int koff = 0;
    if constexpr (MODE == 1) { Ab = (batch == 2) ? A2 : A; Bb = B + batch * Bs; }
    else { Ab = A; Bb = B; koff = (int)batch * (KTILES * 64); }

    const unsigned short* Ag = Ab + (long)bm * kfull + koff;
    const unsigned short* Bg = Bb + (long)bn * kfull + koff;

    f32x4 acc[MF][NF];
#pragma unroll
    for (int i = 0; i < MF; i++)
#pragma unroll
        for (int j = 0; j < NF; j++) acc[i][j] = 0.f;

#pragma unroll
    for (int i = 0; i < LA; i += 2) stage2<BM>(Ag, kfull, lds, i, tid, wid);
#pragma unroll
    for (int i = 0; i < LB; i += 2) stage2<BN>(Bg, kfull, lds + 2 * ATILE, i, tid, wid);
#pragma unroll
    for (int i = 0; i < LB; i += 2) stage2<BN>(Bg + 64, kfull, lds + 2 * ATILE + BTILE, i, tid, wid);
    if constexpr (LB == 4) asm volatile("s_waitcnt vmcnt(4)" ::: "memory");
    else                   asm volatile("s_waitcnt vmcnt(2)" ::: "memory");
    wg_barrier();

#pragma unroll 2
    for (int t = 0; t < KTILES; ++t) {
        short* la  = lds + (t & 1) * ATILE;
        short* laN = lds + ((t + 1) & 1) * ATILE;
        short* lb  = lds + 2 * ATILE + (t & 1) * BTILE;
        const int kA = (t + 1) * 64;
        const int kB = (t + 2) * 64;

        short8 bfrag[NF][2];
#pragma unroll
        for (int q = 0; q < 4; ++q) {
            if (q == 0) {
#pragma unroll
                for (int nf = 0; nf < NF; ++nf)
#pragma unroll
                    for (int kk = 0; kk < 2; ++kk) {
                        const int r = wn * (BN / 4) + nf * 16 + fr;
                        const int cb = kk * 64 + fq * 16;
                        bfrag[nf][kk] = *(const short8*)(lb + r * 64 + ((cb ^ ((r & 7) << 4)) >> 1));
                    }
            }
            short8 afrag[MFP][2];
#pragma unroll
            for (int mf = 0; mf < MFP; ++mf)
#pragma unroll
                for (int kk = 0; kk < 2; ++kk) {
                    const int r = wm * (BM / 2) + q * (BM / 8) + mf * 16 + fr;
                    const int cb = kk * 64 + fq * 16;
                    afrag[mf][kk] = *(const short8*)(la + r * 64 + ((cb ^ ((r & 7) << 4)) >> 1));
                }
            if (t + 1 < KTILES) {
                if (q == 0) stage2<BM>(Ag + kA, kfull, laN, 0, tid, wid);
                if (q == 1 && LA == 4) stage2<BM>(Ag + kA, kfull, laN, 2, tid, wid);
            }
            if (t + 2 < KTILES) {
                if (q == 2) stage2<BN>(Bg + kB, kfull, lb, 0, tid, wid);
                if (q == 3 && LB == 4) stage2<BN>(Bg + kB, kfull, lb, 2, tid, wid);
            }
            wg_barrier();
            __builtin_amdgcn_s_setprio(1);
#pragma unroll
            for (int mf = 0; mf < MFP; ++mf)
#pragma unroll
                for (int nf = 0; nf < NF; ++nf)
#pragma unroll
                    for (int kk = 0; kk < 2; ++kk)
                        acc[q * MFP + mf][nf] = __builtin_amdgcn_mfma_f32_16x16x32_bf16(
                            afrag[mf][kk], bfrag[nf][kk], acc[q * MFP + mf][nf], 0, 0, 0);
            __builtin_amdgcn_s_setprio(0);
            if (q == 3) {
                if (t + 2 < KTILES) {
                    if constexpr (LB == 4) asm volatile("s_waitcnt vmcnt(4)" ::: "memory");
                    else                   asm volatile("s_waitcnt vmcnt(2)" ::: "memory");
                } else {
                    asm volatile("s_waitcnt vmcnt(0)" ::: "memory");
                }
            }
            wg_barrier();
        }
    }

#pragma unroll
    for (int m = 0; m < MF; ++m)
#pragma unroll
        for (int j = 0; j < 4; ++j) {
            const int row = bm + wm * (BM / 2) + m * 16 + fq * 4 + j;
#pragma unroll
            for (int n = 0; n < NF; ++n) {
                const int col = bn + wn * (BN / 4) + n * 16 + fr;
                const float v = acc[m][n][j] * alpha;
                if constexpr (MODE == 1) {
                    unsigned short* C = (unsigned short*)Cout + batch * Cs;
                    C[(long)(col >> 9) * ((long)T_SEQ * EMB) + (long)row * EMB + (col & 511)] = f2b(v);
                } else {
                    float* C = (float*)Cout + batch * ((long)T_SEQ * EMB);
                    C[(long)row * ldc + col] = v;
                }
            }
        }
}

// ============== fused attention: O = (exp(s*QK^T) @ V) / rowsum ==============
// Block = 64 q-rows x 1 head; 8 waves; grid (32 qb, 8 h), head-per-XCD swizzle.
// r8 wave mapping (register-clean: qreg 64 + oacc 64 + sacc 16 ~ 170 VGPR) +
// r9's swz2 S~-store fix (4-way store conflict -> conflict-free; reads stay
// 2-way = free). launch_bounds(512,1): LDS (140KB) pins occupancy at 1
// block/CU anyway; max register headroom. [r9/r10 lesson: 32-rows/wave
// mapping needs ~260 arch VGPRs -> unfixable spill; abandoned.]
// LDS: K[64kv][512e] @0 (64KB, swz (kv&7)<<4 per 1024B row),
//      VT[512d][64kv] @65536 (64KB, swz (d&7)<<4 per 128B row),
//      St[64q][64kv] bf16 @131072 (8KB, swz2 = ((q&7)<<4)^((q&8)<<2) per 128B row),
//      rs[2][64] f32 @139264.
// QK waves (rg=wid>>1, ch=wid&1): rows rg*16..+16, kv cols ch*32..+32
//     (2 frags x 2 k-split accs). Q in regs (16 short8/lane, loaded once).
// PV: wave owns d-slice wid*64..+64: 4m x 4n frags x 2 ksteps from St + VT.
// Pipeline: vmcnt(8) @top (K_t ready, VT_t in flight); vmcnt(0) pre-PV;
// stage K_{t+1} after B2 (K_t reads retired); stage VT_{t+1} after B3.
__global__ __launch_bounds__(512, 1)
void attn_fused(const unsigned short* __restrict__ Qg, const unsigned short* __restrict__ Kg,
                const unsigned short* __restrict__ VTg, unsigned short* __restrict__ Og,
                float scale)
{
    __shared__ __align__(16) short lds[69888];   // 139776 B
    float* rs = (float*)(lds + 69632);           // [2][64] @byte 139264
    char* ldsb = (char*)lds;

    const int tid = threadIdx.x;
    const int wid = tid >> 6, lane = tid & 63;
    const int fr = lane & 15, fq = lane >> 4;
    const int rg = wid >> 1, ch = wid & 1;

    // head-per-XCD: orig%8 = XCD (round-robin dispatch) -> head = f>>5
    const int orig = blockIdx.x + 32 * blockIdx.y;
    const int f = (orig & 7) * 32 + (orig >> 3);
    const int qb = f & 31, h = f >> 5;
    const long TE = (long)T_SEQ * EMB;
    const unsigned short* Qh = Qg + (long)h * TE + (long)(qb * 64) * EMB;
    const unsigned short* Kh = Kg + (long)h * TE;
    const unsigned short* Vh = VTg + (long)h * TE;

    // Q fragments in registers: rows rg*16+fr, k = ks*32 + fq*8
    short8 qreg[16];
#pragma unroll
    for (int ks = 0; ks < 16; ++ks)
        qreg[ks] = *(const short8*)(Qh + (long)(rg * 16 + fr) * EMB + ks * 32 + fq * 8);

    // ---- staging (dest = wave-uniform base; HW adds lane*16) ----
    auto stageK = [&](int kb) {
#pragma unroll
        for (int it = 0; it < 8; ++it) {
            const int c = it * 512 + tid;
            const int kv = c >> 6, s = c & 63;
            gload_lds16(Kh + (long)(kb * 64 + kv) * EMB + (((s * 16) ^ ((kv & 7) << 4)) >> 1),
                        lds + (it * 512 + wid * 64) * 8);
        }
    };
    auto stageV = [&](int kb) {
#pragma unroll
        for (int it = 0; it < 8; ++it) {
            const int c = it * 512 + tid;
            const int d = c >> 3, s = c & 7;
            gload_lds16(Vh + (long)d * T_SEQ + kb * 64 + (((s * 16) ^ ((d & 7) << 4)) >> 1),
                        lds + 32768 + (it * 512 + wid * 64) * 8);
        }
    };

    f32x4 oacc[4][4];
#pragma unroll
    for (int m = 0; m < 4; ++m)
#pragma unroll
        for (int n = 0; n < 4; ++n) oacc[m][n] = 0.f;
    float rsum[4] = {0.f, 0.f, 0.f, 0.f};

    stageK(0);
    stageV(0);

#pragma unroll 1
    for (int t = 0; t < 32; ++t) {
        asm volatile("s_waitcnt vmcnt(8)" ::: "memory");   // K_t landed
        wg_barrier();                                       // B1: K_t visible

        // ---- QK^T: 2 frags (cols ch*32 + c*16), 2 k-split accs each ----
        f32x4 sacc[2][2];
#pragma unroll
        for (int c = 0; c < 2; ++c) { sacc[c][0] = 0.f; sacc[c][1] = 0.f; }
#pragma unroll
        for (int ks = 0; ks < 16; ++ks) {
#pragma unroll
            for (int c = 0; c < 2; ++c) {
                const int kv = (ch * 2 + c) * 16 + fr;
                const short8 bfr = *(const short8*)(ldsb + kv * 1024 +
                                    ((ks * 64 + fq * 16) ^ ((kv & 7) << 4)));
                sacc[c][ks & 1] = __builtin_amdgcn_mfma_f32_16x16x32_bf16(
                    qreg[ks], bfr, sacc[c][ks & 1], 0, 0, 0);
            }
        }
        // ---- exp + rowsum + S~ -> LDS (swz2: disjoint 32B slots per fq-group) ----
#pragma unroll
        for (int c = 0; c < 2; ++c)
#pragma unroll
            for (int j = 0; j < 4; ++j) {
                const float v = __expf(scale * (sacc[c][0][j] + sacc[c][1][j]));
                rsum[j] += v;
                const int row = rg * 16 + fq * 4 + j;
                const int kv = (ch * 2 + c) * 16 + fr;
                *(unsigned short*)(ldsb + 131072 + row * 128 +
                    ((kv * 2) ^ ((row & 7) << 4) ^ ((row & 8) << 2))) = f2b(v);
            }
        asm volatile("s_waitcnt lgkmcnt(0)" ::: "memory");
        asm volatile("s_waitcnt vmcnt(0)" ::: "memory");    // VT_t landed
        wg_barrier();                                        // B2: S~ + VT_t visible; K_t reads retired
        if (t + 1 < 32) stageK(t + 1);

        // ---- PV: O[64 x 64(d-slice)] += S~ @ V ----
#pragma unroll
        for (int kk = 0; kk < 2; ++kk) {
            short8 sa[4], vb[4];
#pragma unroll
            for (int m = 0; m < 4; ++m) {
                const int row = m * 16 + fr;
                sa[m] = *(const short8*)(ldsb + 131072 + row * 128 +
                          ((kk * 64 + fq * 16) ^ ((row & 7) << 4) ^ ((row & 8) << 2)));
            }
#pragma unroll
            for (int n = 0; n < 4; ++n) {
                const int d = wid * 64 + n * 16 + fr;
                vb[n] = *(const short8*)(ldsb + 65536 + d * 128 +
                          ((kk * 64 + fq * 16) ^ ((d & 7) << 4)));
            }
            __builtin_amdgcn_s_setprio(1);
#pragma unroll
            for (int m = 0; m < 4; ++m)
#pragma unroll
                for (int n = 0; n < 4; ++n)
                    oacc[m][n] = __builtin_amdgcn_mfma_f32_16x16x32_bf16(
                        sa[m], vb[n], oacc[m][n], 0, 0, 0);
            __builtin_amdgcn_s_setprio(0);
        }
        wg_barrier();                                        // B3: VT_t + S~ reads retired
        if (t + 1 < 32) stageV(t + 1);
    }

    // ---- rowsum reduce -> rs, then normalize + write O ----
#pragma unroll
    for (int j = 0; j < 4; ++j) {
        float v = rsum[j];
        v += __shfl_xor(v, 1);
        v += __shfl_xor(v, 2);
        v += __shfl_xor(v, 4);
        v += __shfl_xor(v, 8);
        if (fr == 0) rs[ch * 64 + rg * 16 + fq * 4 + j] = v;
    }
    asm volatile("s_waitcnt lgkmcnt(0)" ::: "memory");
    wg_barrier();

#pragma unroll
    for (int m = 0; m < 4; ++m)
#pragma unroll
        for (int j = 0; j < 4; ++j) {
            const int row = m * 16 + fq * 4 + j;
            const float rinv = 1.0f / (rs[row] + rs[64 + row]);
#pragma unroll
            for (int n = 0; n < 4; ++n) {
                const int d = wid * 64 + n * 16 + fr;
                Og[(long)(qb * 64 + row) * HEAD_ALL + h * EMB + d] = f2b(oacc[m][n][j] * rinv);
            }
        }
}

// ---------------- split-K reduce + bias: out = sum_s part[s] + bias ----------------
__global__ void reduce_bias(const float* __restrict__ part, const float* __restrict__ bias,
                            float* __restrict__ out) {
    const int i = blockIdx.x * 256 + threadIdx.x;
    const long stride4 = (long)T_SEQ * EMB / 4;
    const f32x4* p = (const f32x4*)part;
    f32x4 s = p[i];
#pragma unroll
    for (int sl = 1; sl < 8; ++sl) s += p[i + sl * stride4];
    f32x4 b = *(const f32x4*)(bias + ((i * 4) % EMB));
    *((f32x4*)out + i) = s + b;
}

extern "C" void kernel_launch(void* const* d_in, const int* in_sizes, int n_in,
                              void* d_out, int out_size, void* d_ws, size_t ws_size,
                              hipStream_t stream)
{
    const float* x  = (const float*)d_in[0];
    const float* y  = (const float*)d_in[1];
    const float* Wk = (const float*)d_in[2];
    const float* Wq = (const float*)d_in[3];
    const float* Wv = (const float*)d_in[4];
    const float* Wu = (const float*)d_in[5];
    const float* bu = (const float*)d_in[6];
    char* ws = (char*)d_ws;
    const size_t MB = 1024ull * 1024ull;

    // Workspace layout (r7 offsets kept)
    unsigned short* xb   = (unsigned short*)(ws + 0);        // 2 MB  [transient]
    unsigned short* yb   = (unsigned short*)(ws + 2 * MB);   // 2 MB  [transient]
    unsigned short* WT3  = (unsigned short*)(ws + 4 * MB);   // 12 MB: WvT,WkT,WqT [transient]
    unsigned short* PRJ  = (unsigned short*)(ws + 48 * MB);  // Vb@48 [transient], Kb@64, Qb@80
    unsigned short* Vb   = (unsigned short*)(ws + 48 * MB);
    unsigned short* Kb   = (unsigned short*)(ws + 64 * MB);
    unsigned short* Qb   = (unsigned short*)(ws + 80 * MB);
    unsigned short* WuT  = (unsigned short*)(ws + 96 * MB);  // 4 MB
    unsigned short* VTb  = (unsigned short*)(ws + 100 * MB); // 16 MB
    unsigned short* Ob   = (unsigned short*)(ws + 116 * MB); // 16 MB
    float*          part = (float*)(ws + 0);                 // 32 MB f32

    const float scale2 = 0.04419417382415922f;  // 512^-0.5
    const long TE = (long)T_SEQ * EMB;

    // 1) converts
    cvt_bf16_2<<<dim3(512, 2), dim3(256), 0, stream>>>(x, y, xb, yb, T_SEQ * EMB / 8);
    transpose_cvt3_f32<<<dim3(HEAD_ALL / 64, EMB / 64, 3), dim3(256), 0, stream>>>(
        Wv, Wk, Wq, WT3, EMB, HEAD_ALL, (long)2 * MB);
    transpose_cvt3_f32<<<dim3(EMB / 64, HEAD_ALL / 64, 1), dim3(256), 0, stream>>>(
        Wu, nullptr, nullptr, WuT, HEAD_ALL, EMB, 0);

    // 2) fused projections -> [3][h][t][e] bf16 at PRJ (batch0=V(x), 1=K(x), 2=Q(y))
    gemm8p<256, 256, 8, 1><<<dim3(HEAD_ALL / 256, T_SEQ / 256, 3), 512, 0, stream>>>(
        xb, yb, WT3, PRJ, EMB, 1.f, 0, (long)2 * MB, (long)8 * MB, 0);

    // 3) V -> V^T per head
    transpose_bf16<<<dim3(EMB / 64, T_SEQ / 64, NH), dim3(256), 0, stream>>>(
        Vb, VTb, T_SEQ, EMB, TE, TE);

    // 4) fused attention: O = softmax(QK^T * s) @ V  (no-max softmax, fused)
    attn_fused<<<dim3(32, 8), 512, 0, stream>>>(Qb, Kb, VTb, Ob, scale2);

    // 5) split-K=8 final GEMM: part[s] = O @ Wu over K-slice s (K=512 each)
    gemm8p<256, 128, 8, 3><<<dim3(EMB / 128, T_SEQ / 256, 8), 512, 0, stream>>>(
        Ob, nullptr, WuT, part, HEAD_ALL, 1.f, 0, 0, 0, EMB);

    // 6) out = sum(part) + bias, f32
    reduce_bias<<<dim3(T_SEQ * EMB / 4 / 256), dim3(256), 0, stream>>>(part, bu, (float*)d_out);
}